// Round 15
// baseline (91.409 us; speedup 1.0000x reference)
//
#include <hip/hip_runtime.h>
#include <math.h>

#define N_ROWS 4096
#define DIM 256
constexpr float INV_T = 10.0f;

#define NT 32                    // 4096 / 128 tiles per view side
#define NTILES 528               // NT*(NT+1)/2 upper-triangular tiles
#define BM 128
#define PSTRIDE 5120             // [128 rows x 32 (wx,m) | 128 cols x 8 (wy,q)] floats

typedef __attribute__((ext_vector_type(4))) float floatx4;
typedef __attribute__((address_space(3))) unsigned int lds_uint;
typedef const __attribute__((address_space(1))) unsigned int glb_uint;

// Kernel 1: one wave per row. L2-normalize; fp8 e4m3 row-major to R0 (zj_n) /
// R1 (zi_n); pos[r] = dot(zi_n,zj_n)*10 fp32. Thread (0,0) zeroes out.
__global__ __launch_bounds__(256) void normalize_kernel(
    const float* __restrict__ z_i, const float* __restrict__ z_j,
    unsigned char* __restrict__ R0, unsigned char* __restrict__ R1,
    float* __restrict__ pos, float* __restrict__ out)
{
    if (blockIdx.x == 0 && threadIdx.x == 0) out[0] = 0.0f;

    int wave = threadIdx.x >> 6;
    int lane = threadIdx.x & 63;
    int row = blockIdx.x * 4 + wave;

    float4 a = ((const float4*)(z_i + (size_t)row * DIM))[lane];   // k = lane*4..+3
    float4 b = ((const float4*)(z_j + (size_t)row * DIM))[lane];

    float ssa = a.x*a.x + a.y*a.y + a.z*a.z + a.w*a.w;
    float ssb = b.x*b.x + b.y*b.y + b.z*b.z + b.w*b.w;
    float dab = a.x*b.x + a.y*b.y + a.z*b.z + a.w*b.w;
    #pragma unroll
    for (int off = 1; off < 64; off <<= 1) {
        ssa += __shfl_xor(ssa, off);
        ssb += __shfl_xor(ssb, off);
        dab += __shfl_xor(dab, off);
    }
    float ra = rsqrtf(ssa);
    float rb = rsqrtf(ssb);

    int va = __builtin_amdgcn_cvt_pk_fp8_f32(a.x * ra, a.y * ra, 0, false);
    va     = __builtin_amdgcn_cvt_pk_fp8_f32(a.z * ra, a.w * ra, va, true);
    int vb = __builtin_amdgcn_cvt_pk_fp8_f32(b.x * rb, b.y * rb, 0, false);
    vb     = __builtin_amdgcn_cvt_pk_fp8_f32(b.z * rb, b.w * rb, vb, true);

    *(int*)(R1 + (size_t)row * DIM + lane * 4) = va;   // zi_norm
    *(int*)(R0 + (size_t)row * DIM + lane * 4) = vb;   // zj_norm

    if (lane == 0) pos[row] = dab * ra * rb * INV_T;
}

// Kernel 2: symmetric fused fp8 GEMM (R11 one-shot structure) with a
// SHUFFLE-FREE epilogue: each lane stores its raw partials (16 row-partials
// over its 16 columns, 4 col-partials over its 16 rows) with plain stores --
// ZERO cross-lane ops (the __shfl_xor -> ds_swizzle/bpermute latency chains
// are the prime suspect for the invariant ~11us/block). Finalize absorbs the
// 32-way row / 8-way col reduction. No atomics, no counter, no fence.
__global__ __launch_bounds__(256) void gemm_sym(
    const unsigned char* __restrict__ R0,
    const unsigned char* __restrict__ R1,
    float* __restrict__ part)             // [2*NTILES][PSTRIDE]
{
    __shared__ unsigned char As[BM * DIM];   // 32 KB
    __shared__ unsigned char Bs[BM * DIM];   // 32 KB -> 64 KB, 2 blocks/CU

    int view = blockIdx.y;
    const unsigned char* R = view ? R1 : R0;
    float* P = part + (size_t)(view * NTILES + blockIdx.x) * PSTRIDE;

    // triangular decode: blockIdx.x -> (by, bx), bx >= by
    int t = blockIdx.x;
    int by = 0;
    while (t >= NT - by) { t -= NT - by; ++by; }
    int bx = by + t;
    int rT = by * BM, cT = bx * BM;

    int tid = threadIdx.x;
    int lane = tid & 63;
    int wave = tid >> 6;
    int wy = wave >> 1, wx = wave & 1;
    int m = lane & 15, q = lane >> 4;

    // One-shot full-K staging: 2048 16B-slots per tile, source-side swizzle
    // (slot16 p of row r holds chunk16 p^(r&15)).
    #pragma unroll
    for (int stp = 0; stp < 8; ++stp) {
        int s = stp * 256 + tid;
        int row = s >> 4, p = s & 15;
        int cg = p ^ (row & 15);
        const unsigned char* ga = R + (size_t)(rT + row) * DIM + cg * 16;
        const unsigned char* gb = R + (size_t)(cT + row) * DIM + cg * 16;
        __builtin_amdgcn_global_load_lds((glb_uint*)ga, (lds_uint*)&As[s * 16], 16, 0, 0);
        __builtin_amdgcn_global_load_lds((glb_uint*)gb, (lds_uint*)&Bs[s * 16], 16, 0, 0);
    }
    __syncthreads();   // single barrier (compiler adds the vmcnt(0) drain)

    floatx4 acc[4][4] = {};
    #pragma unroll
    for (int kk = 0; kk < 8; ++kk) {
        long af[4], bf[4];
        int c = kk * 4 + q;
        int ch = c >> 1, hh = (c & 1) * 8;
        #pragma unroll
        for (int tr = 0; tr < 4; ++tr) {
            int ra = wy * 64 + tr * 16 + m;
            af[tr] = *(const long*)&As[ra * DIM + (ch ^ (ra & 15)) * 16 + hh];
            int rb = wx * 64 + tr * 16 + m;
            bf[tr] = *(const long*)&Bs[rb * DIM + (ch ^ (rb & 15)) * 16 + hh];
        }
        #pragma unroll
        for (int i = 0; i < 4; ++i)
            #pragma unroll
            for (int j = 0; j < 4; ++j)
                acc[i][j] = __builtin_amdgcn_mfma_f32_16x16x32_fp8_fp8(af[i], bf[j], acc[i][j], 0, 0, 0);
    }

    // Epilogue. C/D layout: col = m, row = q*4 + r (dtype-independent).
    // rs[i][r]: sum of exp over this lane's 16 columns, for row wy*64+i*16+q*4+r.
    // cs[j]:    sum of exp over this lane's 16 rows, for column wx*64+j*16+m.
    float rs[4][4] = {};
    float cs[4] = {0.f, 0.f, 0.f, 0.f};
    #pragma unroll
    for (int i = 0; i < 4; ++i)
        #pragma unroll
        for (int j = 0; j < 4; ++j) {
            int gcol = cT + wx * 64 + j * 16 + m;
            #pragma unroll
            for (int r = 0; r < 4; ++r) {
                int grow = rT + wy * 64 + i * 16 + q * 4 + r;
                float e = (grow == gcol) ? 0.0f : __expf(acc[i][j][r] * INV_T);
                rs[i][r] += e;
                cs[j] += e;
            }
        }
    // Plain per-lane stores, no cross-lane ops.
    // Row partials: P[row*32 + wx*16 + m], row = wy*64+i*16+q*4+r.
    #pragma unroll
    for (int i = 0; i < 4; ++i)
        #pragma unroll
        for (int r = 0; r < 4; ++r)
            P[(wy * 64 + i * 16 + q * 4 + r) * 32 + wx * 16 + m] = rs[i][r];
    // Col partials: P[4096 + col*8 + wy*4 + q], col = wx*64+j*16+m.
    int dz = (bx == by);
    #pragma unroll
    for (int j = 0; j < 4; ++j)
        P[4096 + (wx * 64 + j * 16 + m) * 8 + wy * 4 + q] = dz ? 0.0f : cs[j];
}

// Kernel 3: per-row denom gather + loss. 4 lanes per row split the tile loop;
// cheap shuffle reduce (fine here -- tiny kernel), one atomicAdd per wave.
__global__ __launch_bounds__(256) void finalize_kernel(
    const float* __restrict__ part, const float* __restrict__ pos,
    float* __restrict__ out)
{
    int g = blockIdx.x * 256 + threadIdx.x;      // 0..32767
    int row = g >> 2, sl = g & 3;
    int v = row >> 12, r = row & (N_ROWS - 1);
    int b = r >> 7, l = r & 127;
    const float* Pv = part + (size_t)v * NTILES * PSTRIDE;

    float d = 0.f;
    int t0 = b * NT - (b * (b - 1)) / 2;         // tile (b, b)
    for (int k = sl; k < NT - b; k += 4) {       // row parts: tiles (b, bx>=b)
        const float* T = Pv + (size_t)(t0 + k) * PSTRIDE + l * 32;
        #pragma unroll
        for (int x = 0; x < 8; ++x) {
            float4 vv = ((const float4*)T)[x];
            d += vv.x + vv.y + vv.z + vv.w;
        }
    }
    for (int by2 = sl; by2 <= b; by2 += 4) {     // col parts: tiles (by<=b, b)
        int tb = by2 * NT - (by2 * (by2 - 1)) / 2 + (b - by2);
        const float* T = Pv + (size_t)tb * PSTRIDE + 4096 + l * 8;
        #pragma unroll
        for (int x = 0; x < 2; ++x) {
            float4 vv = ((const float4*)T)[x];
            d += vv.x + vv.y + vv.z + vv.w;
        }
    }
    d += __shfl_xor(d, 1);
    d += __shfl_xor(d, 2);                       // full denom in all 4 lanes
    float p = pos[r];
    float s = (sl == 0) ? (__logf(d + __expf(p)) - p) : 0.0f;
    #pragma unroll
    for (int off = 4; off < 64; off <<= 1) s += __shfl_xor(s, off);
    s += __shfl_xor(s, 1);
    s += __shfl_xor(s, 2);
    if ((threadIdx.x & 63) == 0)
        atomicAdd(out, s * (1.0f / (2 * N_ROWS)));
}

extern "C" void kernel_launch(void* const* d_in, const int* in_sizes, int n_in,
                              void* d_out, int out_size, void* d_ws, size_t ws_size,
                              hipStream_t stream) {
    const float* z_i = (const float*)d_in[0];
    const float* z_j = (const float*)d_in[1];
    char* ws = (char*)d_ws;
    unsigned char* R0 = (unsigned char*)ws;                          // 1 MB fp8
    unsigned char* R1 = (unsigned char*)(ws + (1u << 20));           // 1 MB fp8
    float* pos  = (float*)(ws + (2u << 20));                         // 16 KB
    float* part = (float*)(ws + (2u << 20) + (64u << 10));           // 21.6 MB

    normalize_kernel<<<N_ROWS / 4, 256, 0, stream>>>(z_i, z_j, R0, R1, pos,
                                                     (float*)d_out);
    dim3 grid(NTILES, 2);
    gemm_sym<<<grid, 256, 0, stream>>>(R0, R1, part);
    finalize_kernel<<<4 * 2 * N_ROWS / 256, 256, 0, stream>>>(part, pos, (float*)d_out);
}

// Round 16
// 87.649 us; speedup vs baseline: 1.0429x; 1.0429x over previous
//
#include <hip/hip_runtime.h>
#include <math.h>

#define N_ROWS 4096
#define DIM 256
constexpr float INV_T = 10.0f;

#define NT 32                   // 4096 / 128 tiles per view side
#define NTILES 528              // NT*(NT+1)/2 upper-triangular tiles
#define BM 128
#define PSTRIDE 512             // [2x128 row partials (per wx) | 2x128 col partials (per wy)]

typedef __attribute__((ext_vector_type(4))) float floatx4;  // fp32x4 accumulator

typedef __attribute__((address_space(3))) unsigned int lds_uint;
typedef const __attribute__((address_space(1))) unsigned int glb_uint;

// ===== FINAL KERNEL (session best: 88.0 us, absmax 0.0) =====
// Decomposition: loss = mean(log(denom_r + e^{pos_r}) - pos_r) where denom_r
// needs only SAME-VIEW off-diagonal exp(cos/T) sums -> two symmetric 4096^2
// x256 GEMMs, upper-triangular tiles only (row+col sums cover the mirror).
// Session-validated design rules baked in:
//  - fp8 e4m3 operands (absmax 0.0 vs fp32 ref; 2 MB working set, L2-resident)
//  - one-shot full-K LDS staging via global_load_lds(16B), single barrier
//    (explicit dbuf/vmcnt pipelining: neutral -- R8/R14; m97 plateau)
//  - source-side XOR swizzle, no padding (global_load_lds needs linear dst)
//  - NO atomics / completion counters / fences in the hot kernel (R2 wbl2
//    disaster, R5/R6 +15us, R13 regression) -- plain stores + stream order
//  - 3 small dispatches beat any fusion (R12 mega-fusion -14us regression)

// Kernel 1: one wave per row. L2-normalize; fp8 e4m3 row-major to R0 (zj_n) /
// R1 (zi_n); pos[r] = dot(zi_n,zj_n)*10 fp32. Thread (0,0) zeroes out.
__global__ __launch_bounds__(256) void normalize_kernel(
    const float* __restrict__ z_i, const float* __restrict__ z_j,
    unsigned char* __restrict__ R0, unsigned char* __restrict__ R1,
    float* __restrict__ pos, float* __restrict__ out)
{
    if (blockIdx.x == 0 && threadIdx.x == 0) out[0] = 0.0f;

    int wave = threadIdx.x >> 6;
    int lane = threadIdx.x & 63;
    int row = blockIdx.x * 4 + wave;

    float4 a = ((const float4*)(z_i + (size_t)row * DIM))[lane];   // k = lane*4..+3
    float4 b = ((const float4*)(z_j + (size_t)row * DIM))[lane];

    float ssa = a.x*a.x + a.y*a.y + a.z*a.z + a.w*a.w;
    float ssb = b.x*b.x + b.y*b.y + b.z*b.z + b.w*b.w;
    float dab = a.x*b.x + a.y*b.y + a.z*b.z + a.w*b.w;
    #pragma unroll
    for (int off = 1; off < 64; off <<= 1) {
        ssa += __shfl_xor(ssa, off);
        ssb += __shfl_xor(ssb, off);
        dab += __shfl_xor(dab, off);
    }
    float ra = rsqrtf(ssa);
    float rb = rsqrtf(ssb);

    int va = __builtin_amdgcn_cvt_pk_fp8_f32(a.x * ra, a.y * ra, 0, false);
    va     = __builtin_amdgcn_cvt_pk_fp8_f32(a.z * ra, a.w * ra, va, true);
    int vb = __builtin_amdgcn_cvt_pk_fp8_f32(b.x * rb, b.y * rb, 0, false);
    vb     = __builtin_amdgcn_cvt_pk_fp8_f32(b.z * rb, b.w * rb, vb, true);

    *(int*)(R1 + (size_t)row * DIM + lane * 4) = va;   // zi_norm
    *(int*)(R0 + (size_t)row * DIM + lane * 4) = vb;   // zj_norm

    if (lane == 0) pos[row] = dab * ra * rb * INV_T;
}

// Kernel 2: symmetric fused fp8 GEMM, upper-triangular 128x128 tiles (x2 views).
// ONE-SHOT full-K staging: both 32 KB fp8 tiles DMA'd to LDS via
// global_load_lds(16B), then a SINGLE vmcnt(0)+barrier, then 8 uninterrupted
// K-steps (ds_read_b64 frags + mfma_f32_16x16x32_fp8_fp8).
// Source-side swizzle at 16B granularity: LDS slot16 p of row r holds source
// chunk16 p^(r&15). Epilogue: exp(10*S), diagonal excluded; ROW partials per
// (tile,wx-wave), COL partials per (tile,wy-wave), plain stores, unique slot
// per wave. 64 KB LDS -> 2 blocks/CU.
__global__ __launch_bounds__(256) void gemm_sym(
    const unsigned char* __restrict__ R0,
    const unsigned char* __restrict__ R1,
    float* __restrict__ part)             // [2][NTILES][PSTRIDE]
{
    __shared__ unsigned char As[BM * DIM];   // 32 KB
    __shared__ unsigned char Bs[BM * DIM];   // 32 KB

    int view = blockIdx.y;
    const unsigned char* R = view ? R1 : R0;
    float* P = part + (size_t)(view * NTILES + blockIdx.x) * PSTRIDE;

    // triangular decode: blockIdx.x -> (by, bx), bx >= by
    int t = blockIdx.x;
    int by = 0;
    while (t >= NT - by) { t -= NT - by; ++by; }
    int bx = by + t;
    int rT = by * BM, cT = bx * BM;

    int tid = threadIdx.x;
    int lane = tid & 63;
    int wave = tid >> 6;
    int wy = wave >> 1, wx = wave & 1;
    int m = lane & 15, q = lane >> 4;

    // Stage both tiles: 2048 16B-slots each (128 rows x 16 chunk16).
    #pragma unroll
    for (int stp = 0; stp < 8; ++stp) {
        int s = stp * 256 + tid;              // lane-contiguous slot id
        int row = s >> 4, p = s & 15;
        int cg = p ^ (row & 15);              // source chunk16 for this slot
        const unsigned char* ga = R + (size_t)(rT + row) * DIM + cg * 16;
        const unsigned char* gb = R + (size_t)(cT + row) * DIM + cg * 16;
        __builtin_amdgcn_global_load_lds((glb_uint*)ga, (lds_uint*)&As[s * 16], 16, 0, 0);
        __builtin_amdgcn_global_load_lds((glb_uint*)gb, (lds_uint*)&Bs[s * 16], 16, 0, 0);
    }
    __syncthreads();   // the ONLY barrier (compiler adds the vmcnt(0) drain here)

    floatx4 acc[4][4] = {};

    #pragma unroll
    for (int kk = 0; kk < 8; ++kk) {
        long af[4], bf[4];
        int c = kk * 4 + q;                   // 8B chunk index 0..31
        int ch = c >> 1, hh = (c & 1) * 8;    // chunk16, half offset
        #pragma unroll
        for (int tt = 0; tt < 4; ++tt) {
            int ra = wy * 64 + tt * 16 + m;
            af[tt] = *(const long*)&As[ra * DIM + (ch ^ (ra & 15)) * 16 + hh];
            int rb = wx * 64 + tt * 16 + m;
            bf[tt] = *(const long*)&Bs[rb * DIM + (ch ^ (rb & 15)) * 16 + hh];
        }
        #pragma unroll
        for (int i = 0; i < 4; ++i)
            #pragma unroll
            for (int j = 0; j < 4; ++j)
                acc[i][j] = __builtin_amdgcn_mfma_f32_16x16x32_fp8_fp8(af[i], bf[j], acc[i][j], 0, 0, 0);
    }

    // Epilogue. C/D layout: col = m, row = q*4 + r (m89/m91, dtype-independent).
    float rs[4][4] = {};
    float cs[4] = {0.f, 0.f, 0.f, 0.f};
    #pragma unroll
    for (int i = 0; i < 4; ++i) {
        #pragma unroll
        for (int j = 0; j < 4; ++j) {
            int gcol = cT + wx * 64 + j * 16 + m;
            #pragma unroll
            for (int r = 0; r < 4; ++r) {
                int grow = rT + wy * 64 + i * 16 + q * 4 + r;
                float e = (grow == gcol) ? 0.0f : __expf(acc[i][j][r] * INV_T);
                rs[i][r] += e;
                cs[j] += e;
            }
        }
    }
    // Row partials: reduce over the 16 column-lanes (m); per-(wx,wy) slot.
    #pragma unroll
    for (int off = 1; off < 16; off <<= 1)
        #pragma unroll
        for (int i = 0; i < 4; ++i)
            #pragma unroll
            for (int r = 0; r < 4; ++r)
                rs[i][r] += __shfl_xor(rs[i][r], off);
    if (m == 0) {
        #pragma unroll
        for (int i = 0; i < 4; ++i) {
            float4 v = make_float4(rs[i][0], rs[i][1], rs[i][2], rs[i][3]);
            *(float4*)&P[wx * 128 + wy * 64 + i * 16 + q * 4] = v;
        }
    }
    // Col partials: reduce over the 4 row-quads (q); per-(wy,wx) slot.
    #pragma unroll
    for (int off = 16; off < 64; off <<= 1)
        #pragma unroll
        for (int j = 0; j < 4; ++j)
            cs[j] += __shfl_xor(cs[j], off);
    if (q == 0) {
        #pragma unroll
        for (int j = 0; j < 4; ++j)
            P[256 + wy * 128 + wx * 64 + j * 16 + m] = (bx == by) ? 0.0f : cs[j];
    }
}

// Kernel 3: per-row denom gather (L2-resident) + loss reduce.
__global__ __launch_bounds__(256) void finalize_kernel(
    const float* __restrict__ part, const float* __restrict__ pos,
    float* __restrict__ out)
{
    int g = blockIdx.x * 256 + threadIdx.x;      // 0..8191
    int v = g >> 12, r = g & (N_ROWS - 1);
    int b = r >> 7, l = r & 127;
    const float* P = part + (size_t)v * NTILES * PSTRIDE;

    float d = 0.f;
    int t0 = b * NT - (b * (b - 1)) / 2;         // tile (b, b)
    for (int k = 0; k < NT - b; ++k) {           // row parts: tiles (b, bx>=b)
        const float* T = P + (size_t)(t0 + k) * PSTRIDE;
        d += T[l] + T[128 + l];                  // both wx halves
    }
    for (int by = 0; by <= b; ++by) {            // col parts: tiles (by<=b, b)
        int tb = by * NT - (by * (by - 1)) / 2 + (b - by);
        const float* T = P + (size_t)tb * PSTRIDE;
        d += T[256 + l] + T[384 + l];            // both wy halves
    }
    float p = pos[r];
    float s = __logf(d + __expf(p)) - p;
    #pragma unroll
    for (int off = 1; off < 64; off <<= 1) s += __shfl_xor(s, off);
    if ((threadIdx.x & 63) == 0)
        atomicAdd(out, s * (1.0f / (2 * N_ROWS)));
}

extern "C" void kernel_launch(void* const* d_in, const int* in_sizes, int n_in,
                              void* d_out, int out_size, void* d_ws, size_t ws_size,
                              hipStream_t stream) {
    const float* z_i = (const float*)d_in[0];
    const float* z_j = (const float*)d_in[1];
    char* ws = (char*)d_ws;
    unsigned char* R0 = (unsigned char*)ws;                          // 1 MB fp8
    unsigned char* R1 = (unsigned char*)(ws + (1u << 20));           // 1 MB fp8
    float* pos  = (float*)(ws + (2u << 20));                         // 16 KB
    float* part = (float*)(ws + (2u << 20) + (64u << 10));           // 2.16 MB

    normalize_kernel<<<N_ROWS / 4, 256, 0, stream>>>(z_i, z_j, R0, R1, pos,
                                                     (float*)d_out);
    dim3 grid(NTILES, 2);
    gemm_sym<<<grid, 256, 0, stream>>>(R0, R1, part);
    finalize_kernel<<<2 * N_ROWS / 256, 256, 0, stream>>>(part, pos, (float*)d_out);
}